// Round 3
// baseline (471.004 us; speedup 1.0000x reference)
//
#include <hip/hip_runtime.h>
#include <hip/hip_bf16.h>

#define N_NODES 50000
#define N_EDGES 800000
#define D 64

// ---------------------------------------------------------------------------
// Workspace layout:
//   out_deg : int[N_NODES]      (memset 0)
//   head    : int[N_NODES]      (memset 0xFF -> -1)
//   next    : int[N_EDGES]
//   y       : float[N_NODES*D]
// ---------------------------------------------------------------------------
#define OUTDEG_OFF  0
#define HEAD_OFF    (OUTDEG_OFF + N_NODES * 4)
#define NEXT_OFF    (HEAD_OFF + N_NODES * 4)
#define Y_OFF       (NEXT_OFF + N_EDGES * 4)

// Fused: out-degree histogram + dst-bucketed linked-list build.
__global__ void build_kernel(const int* __restrict__ src,
                             const int* __restrict__ dst,
                             int* __restrict__ out_deg,
                             int* __restrict__ head,
                             int* __restrict__ next) {
    int e = blockIdx.x * blockDim.x + threadIdx.x;
    if (e < N_EDGES) {
        atomicAdd(&out_deg[src[e]], 1);
        next[e] = atomicExch(&head[dst[e]], e);
    }
}

// y[n][:] = rsqrt(max(out_deg[n],1)) * (x[n][:] @ W)
// Block 256 threads = 32 nodes. Thread: 2 nodes x 4 cols, float4/b128 loads.
#define TN 32
__global__ void transform_kernel(const float* __restrict__ x,
                                 const int* __restrict__ out_deg,
                                 const float* __restrict__ W,
                                 float* __restrict__ y) {
    __shared__ float Ws[D * D];
    for (int i = threadIdx.x; i < D * D; i += 256) Ws[i] = W[i];
    __syncthreads();

    int jg = threadIdx.x & 15;        // cols [4*jg, 4*jg+4)
    int pr = threadIdx.x >> 4;        // node pair index 0..15
    int n0 = blockIdx.x * TN + pr * 2;
    int n1 = n0 + 1;
    bool v0 = n0 < N_NODES, v1 = n1 < N_NODES;
    const float* x0 = x + (size_t)(v0 ? n0 : 0) * D;
    const float* x1 = x + (size_t)(v1 ? n1 : 0) * D;

    float a00 = 0.f, a01 = 0.f, a02 = 0.f, a03 = 0.f;
    float a10 = 0.f, a11 = 0.f, a12 = 0.f, a13 = 0.f;

#pragma unroll
    for (int k = 0; k < D; k += 4) {
        float4 xa = *(const float4*)(x0 + k);
        float4 xb = *(const float4*)(x1 + k);
        const float* wr = &Ws[k * D + 4 * jg];
        float4 w0 = *(const float4*)(wr);
        float4 w1 = *(const float4*)(wr + D);
        float4 w2 = *(const float4*)(wr + 2 * D);
        float4 w3 = *(const float4*)(wr + 3 * D);

        a00 = fmaf(xa.x, w0.x, a00); a01 = fmaf(xa.x, w0.y, a01);
        a02 = fmaf(xa.x, w0.z, a02); a03 = fmaf(xa.x, w0.w, a03);
        a00 = fmaf(xa.y, w1.x, a00); a01 = fmaf(xa.y, w1.y, a01);
        a02 = fmaf(xa.y, w1.z, a02); a03 = fmaf(xa.y, w1.w, a03);
        a00 = fmaf(xa.z, w2.x, a00); a01 = fmaf(xa.z, w2.y, a01);
        a02 = fmaf(xa.z, w2.z, a02); a03 = fmaf(xa.z, w2.w, a03);
        a00 = fmaf(xa.w, w3.x, a00); a01 = fmaf(xa.w, w3.y, a01);
        a02 = fmaf(xa.w, w3.z, a02); a03 = fmaf(xa.w, w3.w, a03);

        a10 = fmaf(xb.x, w0.x, a10); a11 = fmaf(xb.x, w0.y, a11);
        a12 = fmaf(xb.x, w0.z, a12); a13 = fmaf(xb.x, w0.w, a13);
        a10 = fmaf(xb.y, w1.x, a10); a11 = fmaf(xb.y, w1.y, a11);
        a12 = fmaf(xb.y, w1.z, a12); a13 = fmaf(xb.y, w1.w, a13);
        a10 = fmaf(xb.z, w2.x, a10); a11 = fmaf(xb.z, w2.y, a11);
        a12 = fmaf(xb.z, w2.z, a12); a13 = fmaf(xb.z, w2.w, a13);
        a10 = fmaf(xb.w, w3.x, a10); a11 = fmaf(xb.w, w3.y, a11);
        a12 = fmaf(xb.w, w3.z, a12); a13 = fmaf(xb.w, w3.w, a13);
    }

    if (v0) {
        float s = rsqrtf(fmaxf((float)out_deg[n0], 1.0f));
        *(float4*)&y[(size_t)n0 * D + 4 * jg] =
            make_float4(a00 * s, a01 * s, a02 * s, a03 * s);
    }
    if (v1) {
        float s = rsqrtf(fmaxf((float)out_deg[n1], 1.0f));
        *(float4*)&y[(size_t)n1 * D + 4 * jg] =
            make_float4(a10 * s, a11 * s, a12 * s, a13 * s);
    }
}

// One wave per node: traverse dst linked list, sum y rows, count in-degree.
__global__ void gather_kernel(const float* __restrict__ y,
                              const int* __restrict__ head,
                              const int* __restrict__ next,
                              const int* __restrict__ src,
                              const float* __restrict__ b,
                              float* __restrict__ out) {
    int lane = threadIdx.x & 63;
    int n = blockIdx.x * (blockDim.x >> 6) + (threadIdx.x >> 6);
    if (n >= N_NODES) return;
    int e = head[n];
    float sum = 0.0f;
    int cnt = 0;
    while (e >= 0) {
        int s = src[e];
        int en = next[e];
        sum += y[(size_t)s * D + lane];
        cnt++;
        e = en;
    }
    float nd = rsqrtf(fmaxf((float)cnt, 1.0f));
    out[(size_t)n * D + lane] = nd * sum + b[lane];
}

extern "C" void kernel_launch(void* const* d_in, const int* in_sizes, int n_in,
                              void* d_out, int out_size, void* d_ws, size_t ws_size,
                              hipStream_t stream) {
    const float* x   = (const float*)d_in[0];
    const int*   src = (const int*)d_in[1];
    const int*   dst = (const int*)d_in[2];
    const float* W   = (const float*)d_in[3];
    const float* b   = (const float*)d_in[4];
    float* out = (float*)d_out;

    char* ws = (char*)d_ws;
    int*   outdeg = (int*)(ws + OUTDEG_OFF);
    int*   head   = (int*)(ws + HEAD_OFF);
    int*   next   = (int*)(ws + NEXT_OFF);
    float* y      = (float*)(ws + Y_OFF);

    hipMemsetAsync(outdeg, 0, N_NODES * 4, stream);
    hipMemsetAsync(head, 0xFF, N_NODES * 4, stream);  // head = -1

    {
        int threads = 256;
        int blocks = (N_EDGES + threads - 1) / threads;
        build_kernel<<<blocks, threads, 0, stream>>>(src, dst, outdeg, head, next);
    }
    {
        int threads = 256;
        int blocks = (N_NODES + TN - 1) / TN;
        transform_kernel<<<blocks, threads, 0, stream>>>(x, outdeg, W, y);
    }
    {
        int threads = 256;  // 4 waves = 4 nodes per block
        int blocks = (N_NODES + 3) / 4;
        gather_kernel<<<blocks, threads, 0, stream>>>(y, head, next, src, b, out);
    }
}

// Round 4
// 434.746 us; speedup vs baseline: 1.0834x; 1.0834x over previous
//
#include <hip/hip_runtime.h>
#include <hip/hip_bf16.h>

#define N_NODES 50000
#define N_EDGES 800000
#define D 64
#define NBLK ((N_NODES + 255) / 256)   // 196 scan blocks

// ---------------------------------------------------------------------------
// Workspace layout:
//   in_deg   : int[N_NODES]   (memset 0)   \ adjacent -> one memset
//   out_deg  : int[N_NODES]   (memset 0)   /
//   row_ptr  : int[N_NODES]
//   cursor   : int[N_NODES]
//   blocksum : int[256]
//   base     : int[256]
//   edge_src : int[N_EDGES]
//   y        : float[N_NODES*D]
// ---------------------------------------------------------------------------
#define INDEG_OFF    0
#define OUTDEG_OFF   (INDEG_OFF + N_NODES * 4)
#define ROWPTR_OFF   (OUTDEG_OFF + N_NODES * 4)
#define CURSOR_OFF   (ROWPTR_OFF + N_NODES * 4)
#define BLKSUM_OFF   (CURSOR_OFF + N_NODES * 4)
#define BASE_OFF     (BLKSUM_OFF + 256 * 4)
#define EDGESRC_OFF  (BASE_OFF + 256 * 4)
#define Y_OFF        (EDGESRC_OFF + N_EDGES * 4)
#define ZERO_BYTES   (2 * N_NODES * 4)

// 1 thread/edge: both degree histograms.
__global__ void degree_kernel(const int* __restrict__ src,
                              const int* __restrict__ dst,
                              int* __restrict__ out_deg,
                              int* __restrict__ in_deg) {
    int e = blockIdx.x * blockDim.x + threadIdx.x;
    if (e < N_EDGES) {
        atomicAdd(&out_deg[src[e]], 1);
        atomicAdd(&in_deg[dst[e]], 1);
    }
}

// Scan phase 1: per-256-chunk sums.
__global__ void partial_kernel(const int* __restrict__ in_deg,
                               int* __restrict__ blocksum) {
    __shared__ int red[4];
    int i = blockIdx.x * 256 + threadIdx.x;
    int v = (i < N_NODES) ? in_deg[i] : 0;
#pragma unroll
    for (int o = 32; o > 0; o >>= 1) v += __shfl_down(v, o, 64);
    if ((threadIdx.x & 63) == 0) red[threadIdx.x >> 6] = v;
    __syncthreads();
    if (threadIdx.x == 0) blocksum[blockIdx.x] = red[0] + red[1] + red[2] + red[3];
}

// Scan phase 2: exclusive scan of the 196 chunk sums (single block).
__global__ void scanpart_kernel(const int* __restrict__ blocksum,
                                int* __restrict__ base) {
    __shared__ int s[256];
    int t = threadIdx.x;
    int v = (t < NBLK) ? blocksum[t] : 0;
    s[t] = v;
    __syncthreads();
    for (int o = 1; o < 256; o <<= 1) {
        int u = (t >= o) ? s[t - o] : 0;
        __syncthreads();
        s[t] += u;
        __syncthreads();
    }
    if (t < NBLK) base[t] = s[t] - v;  // exclusive
}

// Scan phase 3: local exclusive scan + chunk base -> row_ptr, cursor.
__global__ void localscan_kernel(const int* __restrict__ in_deg,
                                 const int* __restrict__ base,
                                 int* __restrict__ row_ptr,
                                 int* __restrict__ cursor) {
    __shared__ int s[256];
    int t = threadIdx.x;
    int i = blockIdx.x * 256 + t;
    int v = (i < N_NODES) ? in_deg[i] : 0;
    s[t] = v;
    __syncthreads();
    for (int o = 1; o < 256; o <<= 1) {
        int u = (t >= o) ? s[t - o] : 0;
        __syncthreads();
        s[t] += u;
        __syncthreads();
    }
    if (i < N_NODES) {
        int ex = base[blockIdx.x] + s[t] - v;
        row_ptr[i] = ex;
        cursor[i] = ex;
    }
}

// Bucket edges by dst: edge_src[pos] = src.
__global__ void fill_kernel(const int* __restrict__ src,
                            const int* __restrict__ dst,
                            int* __restrict__ cursor,
                            int* __restrict__ edge_src) {
    int e = blockIdx.x * blockDim.x + threadIdx.x;
    if (e < N_EDGES) {
        int pos = atomicAdd(&cursor[dst[e]], 1);
        edge_src[pos] = src[e];
    }
}

// y[n][:] = rsqrt(max(out_deg[n],1)) * (x[n][:] @ W)
// Block 256 = 32 nodes; x tile + W staged in LDS via coalesced float4.
#define TN 32
__global__ void transform_kernel(const float* __restrict__ x,
                                 const int* __restrict__ out_deg,
                                 const float* __restrict__ W,
                                 float* __restrict__ y) {
    __shared__ float Ws[D * D];
    __shared__ float xs[TN * D];
    {
        const float4* W4 = (const float4*)W;
        float4* Ws4 = (float4*)Ws;
        for (int i = threadIdx.x; i < D * D / 4; i += 256) Ws4[i] = W4[i];
    }
    int nbase = blockIdx.x * TN;
    int nrows = min(TN, N_NODES - nbase);
    {
        const float4* x4 = (const float4*)(x + (size_t)nbase * D);
        float4* xs4 = (float4*)xs;
        int cnt = nrows * (D / 4);
        for (int i = threadIdx.x; i < cnt; i += 256) xs4[i] = x4[i];
    }
    __syncthreads();

    int jg = threadIdx.x & 15;        // cols [4*jg, 4*jg+4)
    int pr = threadIdx.x >> 4;        // node pair 0..15
    int r0 = pr * 2, r1 = r0 + 1;
    int n0 = nbase + r0, n1 = nbase + r1;
    bool v0 = n0 < N_NODES, v1 = n1 < N_NODES;
    const float* x0 = xs + r0 * D;
    const float* x1 = xs + (v1 ? r1 : r0) * D;

    float a00 = 0.f, a01 = 0.f, a02 = 0.f, a03 = 0.f;
    float a10 = 0.f, a11 = 0.f, a12 = 0.f, a13 = 0.f;

#pragma unroll
    for (int k = 0; k < D; k += 4) {
        float4 xa = *(const float4*)(x0 + k);
        float4 xb = *(const float4*)(x1 + k);
        const float* wr = &Ws[k * D + 4 * jg];
        float4 w0 = *(const float4*)(wr);
        float4 w1 = *(const float4*)(wr + D);
        float4 w2 = *(const float4*)(wr + 2 * D);
        float4 w3 = *(const float4*)(wr + 3 * D);

        a00 = fmaf(xa.x, w0.x, a00); a01 = fmaf(xa.x, w0.y, a01);
        a02 = fmaf(xa.x, w0.z, a02); a03 = fmaf(xa.x, w0.w, a03);
        a00 = fmaf(xa.y, w1.x, a00); a01 = fmaf(xa.y, w1.y, a01);
        a02 = fmaf(xa.y, w1.z, a02); a03 = fmaf(xa.y, w1.w, a03);
        a00 = fmaf(xa.z, w2.x, a00); a01 = fmaf(xa.z, w2.y, a01);
        a02 = fmaf(xa.z, w2.z, a02); a03 = fmaf(xa.z, w2.w, a03);
        a00 = fmaf(xa.w, w3.x, a00); a01 = fmaf(xa.w, w3.y, a01);
        a02 = fmaf(xa.w, w3.z, a02); a03 = fmaf(xa.w, w3.w, a03);

        a10 = fmaf(xb.x, w0.x, a10); a11 = fmaf(xb.x, w0.y, a11);
        a12 = fmaf(xb.x, w0.z, a12); a13 = fmaf(xb.x, w0.w, a13);
        a10 = fmaf(xb.y, w1.x, a10); a11 = fmaf(xb.y, w1.y, a11);
        a12 = fmaf(xb.y, w1.z, a12); a13 = fmaf(xb.y, w1.w, a13);
        a10 = fmaf(xb.z, w2.x, a10); a11 = fmaf(xb.z, w2.y, a11);
        a12 = fmaf(xb.z, w2.z, a12); a13 = fmaf(xb.z, w2.w, a13);
        a10 = fmaf(xb.w, w3.x, a10); a11 = fmaf(xb.w, w3.y, a11);
        a12 = fmaf(xb.w, w3.z, a12); a13 = fmaf(xb.w, w3.w, a13);
    }

    if (v0) {
        float s = rsqrtf(fmaxf((float)out_deg[n0], 1.0f));
        *(float4*)&y[(size_t)n0 * D + 4 * jg] =
            make_float4(a00 * s, a01 * s, a02 * s, a03 * s);
    }
    if (v1) {
        float s = rsqrtf(fmaxf((float)out_deg[n1], 1.0f));
        *(float4*)&y[(size_t)n1 * D + 4 * jg] =
            make_float4(a10 * s, a11 * s, a12 * s, a13 * s);
    }
}

// One wave per node: sum y rows over CSR range with 4-deep MLP unroll.
__global__ void gather_kernel(const float* __restrict__ y,
                              const int* __restrict__ row_ptr,
                              const int* __restrict__ cursor,
                              const int* __restrict__ edge_src,
                              const float* __restrict__ b,
                              float* __restrict__ out) {
    int lane = threadIdx.x & 63;
    int n = blockIdx.x * (blockDim.x >> 6) + (threadIdx.x >> 6);
    if (n >= N_NODES) return;
    int beg = row_ptr[n];
    int end = cursor[n];   // == beg + in_deg[n] after fill
    float s0 = 0.f, s1 = 0.f, s2 = 0.f, s3 = 0.f;
    int i = beg;
    for (; i + 4 <= end; i += 4) {
        int e0 = edge_src[i];
        int e1 = edge_src[i + 1];
        int e2 = edge_src[i + 2];
        int e3 = edge_src[i + 3];
        s0 += y[(size_t)e0 * D + lane];
        s1 += y[(size_t)e1 * D + lane];
        s2 += y[(size_t)e2 * D + lane];
        s3 += y[(size_t)e3 * D + lane];
    }
    for (; i < end; i++) s0 += y[(size_t)edge_src[i] * D + lane];
    float sum = (s0 + s1) + (s2 + s3);
    float nd = rsqrtf(fmaxf((float)(end - beg), 1.0f));
    out[(size_t)n * D + lane] = nd * sum + b[lane];
}

extern "C" void kernel_launch(void* const* d_in, const int* in_sizes, int n_in,
                              void* d_out, int out_size, void* d_ws, size_t ws_size,
                              hipStream_t stream) {
    const float* x   = (const float*)d_in[0];
    const int*   src = (const int*)d_in[1];
    const int*   dst = (const int*)d_in[2];
    const float* W   = (const float*)d_in[3];
    const float* b   = (const float*)d_in[4];
    float* out = (float*)d_out;

    char* ws = (char*)d_ws;
    int*   indeg    = (int*)(ws + INDEG_OFF);
    int*   outdeg   = (int*)(ws + OUTDEG_OFF);
    int*   row_ptr  = (int*)(ws + ROWPTR_OFF);
    int*   cursor   = (int*)(ws + CURSOR_OFF);
    int*   blocksum = (int*)(ws + BLKSUM_OFF);
    int*   base     = (int*)(ws + BASE_OFF);
    int*   edge_src = (int*)(ws + EDGESRC_OFF);
    float* y        = (float*)(ws + Y_OFF);

    hipMemsetAsync(ws + INDEG_OFF, 0, ZERO_BYTES, stream);

    {
        int blocks = (N_EDGES + 255) / 256;
        degree_kernel<<<blocks, 256, 0, stream>>>(src, dst, outdeg, indeg);
    }
    partial_kernel<<<NBLK, 256, 0, stream>>>(indeg, blocksum);
    scanpart_kernel<<<1, 256, 0, stream>>>(blocksum, base);
    localscan_kernel<<<NBLK, 256, 0, stream>>>(indeg, base, row_ptr, cursor);
    {
        int blocks = (N_EDGES + 255) / 256;
        fill_kernel<<<blocks, 256, 0, stream>>>(src, dst, cursor, edge_src);
    }
    {
        int blocks = (N_NODES + TN - 1) / TN;
        transform_kernel<<<blocks, 256, 0, stream>>>(x, outdeg, W, y);
    }
    {
        int blocks = (N_NODES + 3) / 4;   // 4 node-waves per block
        gather_kernel<<<blocks, 256, 0, stream>>>(y, row_ptr, cursor, edge_src, b, out);
    }
}